// Round 1
// 169.470 us; speedup vs baseline: 1.0208x; 1.0208x over previous
//
#include <hip/hip_runtime.h>
#include <hip/hip_bf16.h>

// MFMA fragment types (cdna_hip_programming.md §3)
typedef __attribute__((ext_vector_type(8))) short bf16x8;
typedef __attribute__((ext_vector_type(4))) float f32x4;

#define BATCH 64
#define SEQ   128
#define EMB   256
#define ENC   256
#define NIN   64
#define NSL   128

// packed-weight geometry in d_ws (bf16, fragment-major):
//   w1p: [32 kblk][256 n][8 j]  = 65536 bf16 = 128 KB   (slot_enc_W, k=0..255)
//   w2p: [32 kblk][128 n][8 j]  = 32768 bf16 =  64 KB   (slot_dec_W, k=0..255)
#define W1P_ELEMS (32 * 256 * 8)
#define W2P_ELEMS (32 * 128 * 8)

// ---------------------------------------------------------------------------
// prep: transpose fp32 row-major weights into bf16 B-fragment-major layout.
// One thread per (kblk, n) pair: 8 k-strided fp32 reads (each j-step is a
// fully-coalesced 64-lane read), one contiguous 16 B write.
// ---------------------------------------------------------------------------
__global__ __launch_bounds__(256) void prep_kernel(
    const float* __restrict__ slot_enc_W,   // [256][256]
    const float* __restrict__ slot_dec_W,   // [320][128]
    __hip_bfloat16* __restrict__ w1p,
    __hip_bfloat16* __restrict__ w2p)
{
    const int tid = blockIdx.x * 256 + threadIdx.x;   // 48*256 = 12288
    if (tid < 8192) {
        const int n  = tid & 255;
        const int bk = tid >> 8;
        union { bf16x8 v; __hip_bfloat16 h[8]; } u;
        #pragma unroll
        for (int j = 0; j < 8; ++j)
            u.h[j] = __float2bfloat16(slot_enc_W[(bk * 8 + j) * ENC + n]);
        *(bf16x8*)(w1p + (size_t)tid * 8) = u.v;
    } else {
        const int t2 = tid - 8192;                    // 0..4095
        const int n  = t2 & 127;
        const int bk = t2 >> 7;
        union { bf16x8 v; __hip_bfloat16 h[8]; } u;
        #pragma unroll
        for (int j = 0; j < 8; ++j)
            u.h[j] = __float2bfloat16(slot_dec_W[(bk * 8 + j) * NSL + n]);
        *(bf16x8*)(w2p + (size_t)t2 * 8) = u.v;
    }
}

// ---------------------------------------------------------------------------
// fused kernel.
//   blocks 0..511  : slots path, 16 word-rows per block (2 blocks/CU), 4 waves.
//     Stage 0: cooperative gather of 16 token rows -> bf16 LDS tile [16][264]
//     Stage 1: word_enc[16x256] = relu(emb @ W1 + b1)   (wave owns 64 N-cols)
//     Stage 2: slots[16x128]    = word_enc @ W2 + b2 + onehot-row (wave: 32)
//     MFMA 16x16x32 bf16. A from LDS (ds_read_b128, 264-stride -> 2-way
//     conflict = free). B from packed d_ws (global_load_dwordx4, L2-hit,
//     16 lanes x 16 B contiguous per quad).
//   blocks 512..575: doc path, one block per batch row, pure fp32 VALU.
// ---------------------------------------------------------------------------
__global__ __launch_bounds__(256) void fused_kernel(
    const int*   __restrict__ token_ids,
    const int*   __restrict__ all_intents,
    const float* __restrict__ emb_table,
    const float* __restrict__ doc_enc_W,
    const float* __restrict__ doc_enc_b,
    const float* __restrict__ slot_enc_b,
    const float* __restrict__ doc_dec_W,
    const float* __restrict__ doc_dec_b,
    const float* __restrict__ slot_dec_W,   // [320][128], fp32 (one-hot rows)
    const float* __restrict__ slot_dec_b,
    const __hip_bfloat16* __restrict__ w1p,
    const __hip_bfloat16* __restrict__ w2p,
    float* __restrict__ out_intent,         // fp32 [64][64]
    float* __restrict__ out_slots)          // fp32 [8192][128]
{
    // 16896 B: slots path uses two bf16 [16][264] tiles; doc path reuses
    // the same raw buffer as fp32 scratch.
    __shared__ __align__(16) char smem[2 * 16 * 264 * 2];

    const int blk = blockIdx.x;

    if (blk < 512) {
        // ================= slots path =================
        __hip_bfloat16* lds_emb = (__hip_bfloat16*)smem;            // [16][264]
        __hip_bfloat16* lds_we  = (__hip_bfloat16*)(smem + 16 * 264 * 2);

        const int row0 = blk * 16;
        const int wave = threadIdx.x >> 6;
        const int lane = threadIdx.x & 63;
        const int l16  = lane & 15;
        const int quad = lane >> 4;

        // ---------------- stage 0: gather 16 token rows into LDS ----------
        // 1024 float4 total; 4 iters x 256 threads. Consecutive lanes read
        // consecutive 16 B of the same 1 KB token row -> fully coalesced.
        #pragma unroll
        for (int i = 0; i < 4; ++i) {
            const int idx = i * 256 + threadIdx.x;    // 0..1023
            const int r   = idx >> 6;                 // row 0..15
            const int c4  = idx & 63;                 // float4 within row
            const long tok = token_ids[row0 + r];
            const float4 v = *(const float4*)(emb_table + tok * EMB + c4 * 4);
            union { ushort4 s; __hip_bfloat16 h[4]; } u;
            u.h[0] = __float2bfloat16(v.x); u.h[1] = __float2bfloat16(v.y);
            u.h[2] = __float2bfloat16(v.z); u.h[3] = __float2bfloat16(v.w);
            *(ushort4*)(lds_emb + r * 264 + c4 * 4) = u.s;
        }
        __syncthreads();

        // ---------------- stage 1 ----------------
        f32x4 acc[4];
        #pragma unroll
        for (int nt = 0; nt < 4; ++nt)
            acc[nt] = (f32x4){0.f, 0.f, 0.f, 0.f};

        const int nbase1 = wave * 64;
        #pragma unroll
        for (int ks = 0; ks < 8; ++ks) {
            // A: row = l16, k = ks*32 + quad*8 + j  (16 B aligned, 2-way bank = free)
            const bf16x8 a0 = *(const bf16x8*)(lds_emb + l16 * 264 + ks * 32 + quad * 8);
            const int kblk = ks * 4 + quad;
            #pragma unroll
            for (int nt = 0; nt < 4; ++nt) {
                const int n = nbase1 + nt * 16 + l16;
                const bf16x8 bf = *(const bf16x8*)(w1p + ((size_t)kblk * 256 + n) * 8);
                acc[nt] = __builtin_amdgcn_mfma_f32_16x16x32_bf16(a0, bf, acc[nt], 0, 0, 0);
            }
        }

        // relu + bias -> bf16 tile in LDS
        #pragma unroll
        for (int nt = 0; nt < 4; ++nt) {
            const int col = nbase1 + nt * 16 + l16;
            const float bias = slot_enc_b[col];
            #pragma unroll
            for (int r = 0; r < 4; ++r) {
                const int row = quad * 4 + r;   // D: col=lane&15, row=quad*4+reg
                lds_we[row * 264 + col] =
                    __float2bfloat16(fmaxf(acc[nt][r] + bias, 0.f));
            }
        }
        __syncthreads();

        // ---------------- stage 2 ----------------
        f32x4 acc2[2];
        #pragma unroll
        for (int nt = 0; nt < 2; ++nt)
            acc2[nt] = (f32x4){0.f, 0.f, 0.f, 0.f};

        const int nbase2 = wave * 32;
        #pragma unroll
        for (int ks = 0; ks < 8; ++ks) {
            const bf16x8 a0 = *(const bf16x8*)(lds_we + l16 * 264 + ks * 32 + quad * 8);
            const int kblk = ks * 4 + quad;
            #pragma unroll
            for (int nt = 0; nt < 2; ++nt) {
                const int n = nbase2 + nt * 16 + l16;
                const bf16x8 bf = *(const bf16x8*)(w2p + ((size_t)kblk * 128 + n) * 8);
                acc2[nt] = __builtin_amdgcn_mfma_f32_16x16x32_bf16(a0, bf, acc2[nt], 0, 0, 0);
            }
        }

        // epilogue: + slot_dec_b + slot_dec_W[256 + intent[b]] row, fp32 store
        const int intent = all_intents[blk >> 3];          // blk*16/128
        const float* hotrow = slot_dec_W + (long)(256 + intent) * NSL;

        #pragma unroll
        for (int nt = 0; nt < 2; ++nt) {
            const int col = nbase2 + nt * 16 + l16;
            const float add = slot_dec_b[col] + hotrow[col];
            #pragma unroll
            for (int r = 0; r < 4; ++r) {
                const int row = quad * 4 + r;
                out_slots[(long)(row0 + row) * NSL + col] = acc2[nt][r] + add;
            }
        }
    } else {
        // ================= doc path: one block per batch row =================
        float* red  = (float*)smem;                 // [4][256]
        float* sent = (float*)(smem + 4096);        // [256]
        float* senc = (float*)(smem + 4096 + 1024); // [256]

        const int b  = blk - 512;
        const int t  = threadIdx.x;
        const int wv = t >> 6;          // wave id: token-subset
        const int ln = t & 63;          // lane: 4 consecutive cols (float4)
        const int* toks = token_ids + b * SEQ;

        float4 accv = make_float4(0.f, 0.f, 0.f, 0.f);
        #pragma unroll 8
        for (int i = 0; i < 32; ++i) {
            const long tok = toks[wv * 32 + i];
            const float4 v = *(const float4*)(emb_table + tok * EMB + ln * 4);
            accv.x += v.x; accv.y += v.y; accv.z += v.z; accv.w += v.w;
        }
        *(float4*)(&red[wv * 256 + ln * 4]) = accv;
        __syncthreads();

        sent[t] = (red[0 * 256 + t] + red[1 * 256 + t] +
                   red[2 * 256 + t] + red[3 * 256 + t]) * (1.0f / 128.0f);
        __syncthreads();

        float a = doc_enc_b[t];
        #pragma unroll 16
        for (int k = 0; k < EMB; ++k)
            a = fmaf(sent[k], doc_enc_W[k * ENC + t], a);
        senc[t] = fmaxf(a, 0.f);
        __syncthreads();

        if (t < NIN) {
            float a2 = doc_dec_b[t];
            #pragma unroll 16
            for (int k = 0; k < ENC; ++k)
                a2 = fmaf(senc[k], doc_dec_W[k * NIN + t], a2);
            out_intent[b * NIN + t] = a2;
        }
    }
}

// ---------------------------------------------------------------------------
extern "C" void kernel_launch(void* const* d_in, const int* in_sizes, int n_in,
                              void* d_out, int out_size, void* d_ws, size_t ws_size,
                              hipStream_t stream) {
    const int*   token_ids   = (const int*)d_in[0];
    const int*   all_intents = (const int*)d_in[1];
    const float* emb_table   = (const float*)d_in[2];
    const float* doc_enc_W   = (const float*)d_in[3];
    const float* doc_enc_b   = (const float*)d_in[4];
    const float* slot_enc_W  = (const float*)d_in[5];
    const float* slot_enc_b  = (const float*)d_in[6];
    const float* doc_dec_W   = (const float*)d_in[7];
    const float* doc_dec_b   = (const float*)d_in[8];
    const float* slot_dec_W  = (const float*)d_in[9];
    const float* slot_dec_b  = (const float*)d_in[10];

    __hip_bfloat16* w1p = (__hip_bfloat16*)d_ws;
    __hip_bfloat16* w2p = w1p + W1P_ELEMS;

    float* out = (float*)d_out;     // [0,4096): intents fp32; rest: slots fp32

    prep_kernel<<<48, 256, 0, stream>>>(slot_enc_W, slot_dec_W, w1p, w2p);

    fused_kernel<<<576, 256, 0, stream>>>(
        token_ids, all_intents, emb_table, doc_enc_W, doc_enc_b,
        slot_enc_b, doc_dec_W, doc_dec_b, slot_dec_W, slot_dec_b,
        w1p, w2p,
        out, out + BATCH * NIN);
}

// Round 2
// 163.958 us; speedup vs baseline: 1.0551x; 1.0336x over previous
//
#include <hip/hip_runtime.h>
#include <hip/hip_bf16.h>

// MFMA fragment types (cdna_hip_programming.md §3)
typedef __attribute__((ext_vector_type(8))) short bf16x8;
typedef __attribute__((ext_vector_type(4))) float f32x4;

#define BATCH 64
#define SEQ   128
#define EMB   256
#define ENC   256
#define NIN   64
#define NSL   128

// packed-weight geometry in d_ws (bf16, B-fragment-major [kblk][n][j]):
//   w1p  : [32][256][8] = 65536 elems (slot_enc_W, k=0..255)   off 0
//   w2p  : [32][128][8] = 32768 elems (slot_dec_W, k=0..255)   off 65536
//   dw1p : [32][256][8] = 65536 elems (doc_enc_W)              off 98304
//   dw2p : [32][ 64][8] = 16384 elems (doc_dec_W)              off 163840
#define W1P_OFF   0
#define W2P_OFF   65536
#define DW1P_OFF  98304
#define DW2P_OFF  163840

// ---------------------------------------------------------------------------
// prep: transpose fp32 row-major weights into bf16 B-fragment-major layout.
// One thread per (kblk, n): 8 k-strided fp32 reads (each j-step coalesces
// across the n-lanes), one contiguous 16 B write.
// ---------------------------------------------------------------------------
#define PACK(W, NCOLS, DST, IDX) {                                            \
    const int n  = (IDX) & ((NCOLS) - 1);                                     \
    const int bk = (IDX) / (NCOLS);                                           \
    union { bf16x8 v; __hip_bfloat16 h[8]; } u;                               \
    _Pragma("unroll")                                                         \
    for (int j = 0; j < 8; ++j)                                               \
        u.h[j] = __float2bfloat16((W)[(bk * 8 + j) * (NCOLS) + n]);           \
    *(bf16x8*)((DST) + (size_t)(IDX) * 8) = u.v; }

__global__ __launch_bounds__(256) void prep_kernel(
    const float* __restrict__ slot_enc_W,   // [256][256]
    const float* __restrict__ slot_dec_W,   // [320][128] (k rows 0..255 used)
    const float* __restrict__ doc_enc_W,    // [256][256]
    const float* __restrict__ doc_dec_W,    // [256][64]
    __hip_bfloat16* __restrict__ ws)
{
    const int tid = blockIdx.x * 256 + threadIdx.x;   // 88*256 = 22528
    if (tid < 8192) {
        PACK(slot_enc_W, 256, ws + W1P_OFF,  tid);
    } else if (tid < 12288) {
        PACK(slot_dec_W, 128, ws + W2P_OFF,  tid - 8192);
    } else if (tid < 20480) {
        PACK(doc_enc_W,  256, ws + DW1P_OFF, tid - 12288);
    } else {
        PACK(doc_dec_W,   64, ws + DW2P_OFF, tid - 20480);
    }
}

static __device__ __forceinline__ bf16x8 cvt8(const float4 lo, const float4 hi) {
    union { bf16x8 v; __hip_bfloat16 h[8]; } u;
    u.h[0] = __float2bfloat16(lo.x); u.h[1] = __float2bfloat16(lo.y);
    u.h[2] = __float2bfloat16(lo.z); u.h[3] = __float2bfloat16(lo.w);
    u.h[4] = __float2bfloat16(hi.x); u.h[5] = __float2bfloat16(hi.y);
    u.h[6] = __float2bfloat16(hi.z); u.h[7] = __float2bfloat16(hi.w);
    return u.v;
}

// ---------------------------------------------------------------------------
// fused kernel, grid = 512 blocks exactly (2 blocks/CU, no ragged round).
//   every block   : slots path, 16 word-rows (row0 = blk*16), 4 waves.
//   blocks blk&7==0 additionally run the doc path for b = blk>>3 FIRST
//   (long-latency gather + two MFMA projections), so the serial doc chain
//   starts at t=0 and hides under the co-resident slots blocks.
//
// Doc MFMA trick: A-fragment rows are all identical (= sent[k] broadcast
// across l16), so every D row holds the same result; read reg 0.
// ---------------------------------------------------------------------------
__global__ __launch_bounds__(256) void fused_kernel(
    const int*   __restrict__ token_ids,
    const int*   __restrict__ all_intents,
    const float* __restrict__ emb_table,
    const float* __restrict__ doc_enc_b,
    const float* __restrict__ slot_enc_b,
    const float* __restrict__ doc_dec_b,
    const float* __restrict__ slot_dec_W,   // [320][128], fp32 (one-hot rows)
    const float* __restrict__ slot_dec_b,
    const __hip_bfloat16* __restrict__ ws,  // packed weights
    float* __restrict__ out_intent,         // fp32 [64][64]
    float* __restrict__ out_slots)          // fp32 [8192][128]
{
    __shared__ __align__(16) char smem[2 * 16 * 264 * 2];   // 16.9 KB

    const int blk  = blockIdx.x;
    const int wave = threadIdx.x >> 6;
    const int lane = threadIdx.x & 63;
    const int l16  = lane & 15;
    const int quad = lane >> 4;

    const __hip_bfloat16* w1p  = ws + W1P_OFF;
    const __hip_bfloat16* w2p  = ws + W2P_OFF;
    const __hip_bfloat16* dw1p = ws + DW1P_OFF;
    const __hip_bfloat16* dw2p = ws + DW2P_OFF;

    if ((blk & 7) == 0) {
        // ================= doc path for b = blk>>3 =================
        float* red  = (float*)smem;            // [4][256]
        float* sent = (float*)(smem + 4096);   // [256] fp32
        float* senc = (float*)(smem + 5120);   // [256] fp32

        const int b  = blk >> 3;
        const int t  = threadIdx.x;
        const int* toks = token_ids + b * SEQ;

        // mean over 128 token rows (wave -> 32 rows, lane -> 16 B slice)
        float4 accv = make_float4(0.f, 0.f, 0.f, 0.f);
        #pragma unroll 8
        for (int i = 0; i < 32; ++i) {
            const long tok = toks[wave * 32 + i];
            const float4 v = *(const float4*)(emb_table + tok * EMB + lane * 4);
            accv.x += v.x; accv.y += v.y; accv.z += v.z; accv.w += v.w;
        }
        *(float4*)(&red[wave * 256 + lane * 4]) = accv;
        __syncthreads();

        sent[t] = (red[t] + red[256 + t] + red[512 + t] + red[768 + t])
                  * (1.0f / 128.0f);
        __syncthreads();

        // doc encoder: senc = relu(sent @ W + b), wave owns 64 cols
        f32x4 dacc[4];
        #pragma unroll
        for (int nt = 0; nt < 4; ++nt) dacc[nt] = (f32x4){0.f, 0.f, 0.f, 0.f};

        #pragma unroll
        for (int ks = 0; ks < 8; ++ks) {
            const float* sp = sent + ks * 32 + quad * 8;
            const bf16x8 a = cvt8(*(const float4*)sp, *(const float4*)(sp + 4));
            const int kblk = ks * 4 + quad;
            #pragma unroll
            for (int nt = 0; nt < 4; ++nt) {
                const int n = wave * 64 + nt * 16 + l16;
                const bf16x8 bf = *(const bf16x8*)(dw1p + ((size_t)kblk * 256 + n) * 8);
                dacc[nt] = __builtin_amdgcn_mfma_f32_16x16x32_bf16(a, bf, dacc[nt], 0, 0, 0);
            }
        }
        if (quad == 0) {
            #pragma unroll
            for (int nt = 0; nt < 4; ++nt) {
                const int col = wave * 64 + nt * 16 + l16;
                senc[col] = fmaxf(dacc[nt][0] + doc_enc_b[col], 0.f);
            }
        }
        __syncthreads();

        // doc decoder: intent = senc @ Wd + b, wave owns 16 cols
        f32x4 iacc = (f32x4){0.f, 0.f, 0.f, 0.f};
        #pragma unroll
        for (int ks = 0; ks < 8; ++ks) {
            const float* sp = senc + ks * 32 + quad * 8;
            const bf16x8 a = cvt8(*(const float4*)sp, *(const float4*)(sp + 4));
            const int kblk = ks * 4 + quad;
            const int n = wave * 16 + l16;
            const bf16x8 bf = *(const bf16x8*)(dw2p + ((size_t)kblk * 64 + n) * 8);
            iacc = __builtin_amdgcn_mfma_f32_16x16x32_bf16(a, bf, iacc, 0, 0, 0);
        }
        if (quad == 0)
            out_intent[b * NIN + wave * 16 + l16] = iacc[0] + doc_dec_b[wave * 16 + l16];
        __syncthreads();   // senc/LDS reads done before slots phase overwrites
    }

    // ================= slots path (all 512 blocks) =================
    __hip_bfloat16* lds_emb = (__hip_bfloat16*)smem;            // [16][264]
    __hip_bfloat16* lds_we  = (__hip_bfloat16*)(smem + 16 * 264 * 2);

    const int row0 = blk * 16;

    // ---------------- stage 0: gather 16 token rows into LDS ----------
    #pragma unroll
    for (int i = 0; i < 4; ++i) {
        const int idx = i * 256 + threadIdx.x;    // 0..1023
        const int r   = idx >> 6;                 // row 0..15
        const int c4  = idx & 63;                 // float4 within row
        const long tok = token_ids[row0 + r];
        const float4 v = *(const float4*)(emb_table + tok * EMB + c4 * 4);
        union { ushort4 s; __hip_bfloat16 h[4]; } u;
        u.h[0] = __float2bfloat16(v.x); u.h[1] = __float2bfloat16(v.y);
        u.h[2] = __float2bfloat16(v.z); u.h[3] = __float2bfloat16(v.w);
        *(ushort4*)(lds_emb + r * 264 + c4 * 4) = u.s;
    }
    __syncthreads();

    // ---------------- stage 1: word_enc = relu(emb @ W1 + b1) ----------
    f32x4 acc[4];
    #pragma unroll
    for (int nt = 0; nt < 4; ++nt) acc[nt] = (f32x4){0.f, 0.f, 0.f, 0.f};

    const int nbase1 = wave * 64;
    #pragma unroll
    for (int ks = 0; ks < 8; ++ks) {
        const bf16x8 a0 = *(const bf16x8*)(lds_emb + l16 * 264 + ks * 32 + quad * 8);
        const int kblk = ks * 4 + quad;
        #pragma unroll
        for (int nt = 0; nt < 4; ++nt) {
            const int n = nbase1 + nt * 16 + l16;
            const bf16x8 bf = *(const bf16x8*)(w1p + ((size_t)kblk * 256 + n) * 8);
            acc[nt] = __builtin_amdgcn_mfma_f32_16x16x32_bf16(a0, bf, acc[nt], 0, 0, 0);
        }
    }

    #pragma unroll
    for (int nt = 0; nt < 4; ++nt) {
        const int col = nbase1 + nt * 16 + l16;
        const float bias = slot_enc_b[col];
        #pragma unroll
        for (int r = 0; r < 4; ++r) {
            const int row = quad * 4 + r;   // D: col=lane&15, row=quad*4+reg
            lds_we[row * 264 + col] =
                __float2bfloat16(fmaxf(acc[nt][r] + bias, 0.f));
        }
    }
    __syncthreads();

    // ---------------- stage 2: slots = word_enc @ W2 ----------
    f32x4 acc2[2];
    #pragma unroll
    for (int nt = 0; nt < 2; ++nt) acc2[nt] = (f32x4){0.f, 0.f, 0.f, 0.f};

    const int nbase2 = wave * 32;
    #pragma unroll
    for (int ks = 0; ks < 8; ++ks) {
        const bf16x8 a0 = *(const bf16x8*)(lds_we + l16 * 264 + ks * 32 + quad * 8);
        const int kblk = ks * 4 + quad;
        #pragma unroll
        for (int nt = 0; nt < 2; ++nt) {
            const int n = nbase2 + nt * 16 + l16;
            const bf16x8 bf = *(const bf16x8*)(w2p + ((size_t)kblk * 128 + n) * 8);
            acc2[nt] = __builtin_amdgcn_mfma_f32_16x16x32_bf16(a0, bf, acc2[nt], 0, 0, 0);
        }
    }

    // epilogue: + slot_dec_b + slot_dec_W[256 + intent[b]] row, fp32 store
    const int intent = all_intents[blk >> 3];
    const float* hotrow = slot_dec_W + (long)(256 + intent) * NSL;

    #pragma unroll
    for (int nt = 0; nt < 2; ++nt) {
        const int col = nbase2 + nt * 16 + l16;
        const float add = slot_dec_b[col] + hotrow[col];
        #pragma unroll
        for (int r = 0; r < 4; ++r) {
            const int row = quad * 4 + r;
            out_slots[(long)(row0 + row) * NSL + col] = acc2[nt][r] + add;
        }
    }
}

// ---------------------------------------------------------------------------
extern "C" void kernel_launch(void* const* d_in, const int* in_sizes, int n_in,
                              void* d_out, int out_size, void* d_ws, size_t ws_size,
                              hipStream_t stream) {
    const int*   token_ids   = (const int*)d_in[0];
    const int*   all_intents = (const int*)d_in[1];
    const float* emb_table   = (const float*)d_in[2];
    const float* doc_enc_W   = (const float*)d_in[3];
    const float* doc_enc_b   = (const float*)d_in[4];
    const float* slot_enc_W  = (const float*)d_in[5];
    const float* slot_enc_b  = (const float*)d_in[6];
    const float* doc_dec_W   = (const float*)d_in[7];
    const float* doc_dec_b   = (const float*)d_in[8];
    const float* slot_dec_W  = (const float*)d_in[9];
    const float* slot_dec_b  = (const float*)d_in[10];

    __hip_bfloat16* ws = (__hip_bfloat16*)d_ws;
    float* out = (float*)d_out;     // [0,4096): intents fp32; rest: slots fp32

    prep_kernel<<<88, 256, 0, stream>>>(slot_enc_W, slot_dec_W,
                                        doc_enc_W, doc_dec_W, ws);

    fused_kernel<<<512, 256, 0, stream>>>(
        token_ids, all_intents, emb_table, doc_enc_b,
        slot_enc_b, doc_dec_b, slot_dec_W, slot_dec_b,
        ws, out, out + BATCH * NIN);
}